// Round 6
// baseline (1050.493 us; speedup 1.0000x reference)
//
#include <hip/hip_runtime.h>
#include <hip/hip_bf16.h>

#define DEVI __device__ __forceinline__

constexpr int NN = 10000;       // nodes
constexpr int NE = 80000;       // edges
constexpr int AGG_ROWS = 10240; // 80 * 128 — pad so 128-row M-tiles stay in-bounds

typedef __attribute__((ext_vector_type(8))) short bf16x8;  // 8 bf16 (4 VGPRs)
typedef __attribute__((ext_vector_type(4))) float f32x4;   // MFMA acc

// ---------- bf16 helpers (bit-level, RNE) ----------
DEVI float blo(unsigned int u) {
  union { unsigned int i; float f; } c; c.i = u << 16; return c.f;
}
DEVI float bhi(unsigned int u) {
  union { unsigned int i; float f; } c; c.i = u & 0xffff0000u; return c.f;
}
DEVI unsigned short f2b(float f) {
  union { float f; unsigned int i; } c; c.f = f;
  unsigned int i = c.i;
  return (unsigned short)((i + 0x7fffu + ((i >> 16) & 1u)) >> 16);
}
DEVI void st1(float* p, float v) { *p = v; }
DEVI void st1(unsigned short* p, float v) { *p = f2b(v); }
DEVI void store8b(unsigned short* p, const float v[8]) {
  int4 pk;
  pk.x = (int)((unsigned)f2b(v[0]) | ((unsigned)f2b(v[1]) << 16));
  pk.y = (int)((unsigned)f2b(v[2]) | ((unsigned)f2b(v[3]) << 16));
  pk.z = (int)((unsigned)f2b(v[4]) | ((unsigned)f2b(v[5]) << 16));
  pk.w = (int)((unsigned)f2b(v[6]) | ((unsigned)f2b(v[7]) << 16));
  *reinterpret_cast<int4*>(p) = pk;
}

// async global->LDS, 16B per lane (wave-uniform LDS base + lane*16 pattern)
DEVI void gload16(const void* g, void* l) {
  __builtin_amdgcn_global_load_lds(
      (const __attribute__((address_space(1))) void*)g,
      (__attribute__((address_space(3))) void*)l, 16, 0, 0);
}

// ================= CSR build =================
__global__ __launch_bounds__(256)
void hist_kernel(const int* __restrict__ dst, int* __restrict__ cnt) {
  int e = blockIdx.x * 256 + threadIdx.x;
  if (e < NE) atomicAdd(&cnt[dst[e]], 1);
}

__global__ __launch_bounds__(256)
void scan_kernel(const int* __restrict__ cnt, int* __restrict__ off,
                 int* __restrict__ cursor) {
  __shared__ int buf[256];
  __shared__ int carry;
  if (threadIdx.x == 0) carry = 0;
  __syncthreads();
  for (int base = 0; base < NN; base += 256) {
    int i = base + threadIdx.x;
    int v = (i < NN) ? cnt[i] : 0;
    buf[threadIdx.x] = v;
    __syncthreads();
#pragma unroll
    for (int o = 1; o < 256; o <<= 1) {
      int t = (threadIdx.x >= o) ? buf[threadIdx.x - o] : 0;
      __syncthreads();
      buf[threadIdx.x] += t;
      __syncthreads();
    }
    int incl = buf[threadIdx.x];
    int c0 = carry;
    if (i < NN) { int ex = c0 + incl - v; off[i] = ex; cursor[i] = ex; }
    __syncthreads();
    if (threadIdx.x == 255) carry = c0 + incl;
    __syncthreads();
  }
}

__global__ __launch_bounds__(256)
void bucket_kernel(const int* __restrict__ src, const int* __restrict__ dst,
                   int* __restrict__ cursor, int* __restrict__ es) {
  int e = blockIdx.x * 256 + threadIdx.x;
  if (e < NE) {
    int p = atomicAdd(&cursor[dst[e]], 1);
    es[p] = src[e];
  }
}

// ============ weight convert+transpose: W[K][N] f32 -> WT[N][K] bf16 ============
__global__ __launch_bounds__(256)
void transpose_w(const float* __restrict__ W, unsigned short* __restrict__ WT,
                 int K, int N) {
  __shared__ float tile[32][33];
  int tx = threadIdx.x & 31, ty = threadIdx.x >> 5;  // ty 0..7
  int n0 = blockIdx.x * 32, k0 = blockIdx.y * 32;
#pragma unroll
  for (int j = 0; j < 32; j += 8)
    tile[ty + j][tx] = W[(size_t)(k0 + ty + j) * N + n0 + tx];
  __syncthreads();
#pragma unroll
  for (int j = 0; j < 32; j += 8)
    WT[(size_t)(n0 + ty + j) * K + k0 + tx] = f2b(tile[tx][ty + j]);
}

// ================= gather-aggregate (CSR, no atomics, depth-4 edge pipeline) =================
// layer 1: C=128, x f32. One 64-lane wave per node, 2 ch/lane. bf16 out.
__global__ __launch_bounds__(256)
void gather_l1(const float* __restrict__ x, const float* __restrict__ pos,
               const int* __restrict__ off, const int* __restrict__ cnt,
               const int* __restrict__ es,
               const float* __restrict__ Win, const float* __restrict__ bin,
               unsigned short* __restrict__ agg) {
  constexpr int C = 128;
  int lane = threadIdx.x & 63;
  int i = blockIdx.x * 4 + (threadIdx.x >> 6);
  if (i >= NN) return;
  int c = lane * 2;
  float w00 = Win[c], w01 = Win[c + 1];
  float w10 = Win[C + c], w11 = Win[C + c + 1];
  float b0 = bin[c], b1 = bin[c + 1];
  float a0 = 0.f, a1 = 0.f;
  float2 pd = *reinterpret_cast<const float2*>(pos + 2 * i);
  int s0 = off[i], n = cnt[i];   // n is wave-uniform (one node per wave)

  float2 r0, r1, r2, r3, q0, q1, q2, q3;
  auto ld = [&](int k, float2& r, float2& q) {
    if (k < n) {
      int s = es[s0 + k];
      float2 ps = *reinterpret_cast<const float2*>(pos + 2 * s);
      r = make_float2(ps.x - pd.x, ps.y - pd.y);
      q = *reinterpret_cast<const float2*>(x + (size_t)s * C + c);
    }
  };
  auto fma1 = [&](const float2& r, const float2& q) {
    float sc0 = fmaxf(fmaf(r.x, w00, fmaf(r.y, w10, b0)), 0.f);
    float sc1 = fmaxf(fmaf(r.x, w01, fmaf(r.y, w11, b1)), 0.f);
    a0 = fmaf(sc0, q.x, a0);
    a1 = fmaf(sc1, q.y, a1);
  };
  ld(0, r0, q0); ld(1, r1, q1); ld(2, r2, q2); ld(3, r3, q3);
  for (int k = 0; k < n; k += 4) {
    fma1(r0, q0); ld(k + 4, r0, q0);
    if (k + 1 < n) { fma1(r1, q1); } ld(k + 5, r1, q1);
    if (k + 2 < n) { fma1(r2, q2); } ld(k + 6, r2, q2);
    if (k + 3 < n) { fma1(r3, q3); } ld(k + 7, r3, q3);
  }
  unsigned int pk = (unsigned)f2b(a0) | ((unsigned)f2b(a1) << 16);
  *reinterpret_cast<unsigned int*>(agg + (size_t)i * C + c) = pk;
}

// layers 2/3: C=2048, x bf16. One 256-thread block per node, 8 ch/thread. bf16 out.
__global__ __launch_bounds__(256)
void gather_c2048(const unsigned short* __restrict__ x, const float* __restrict__ pos,
                  const int* __restrict__ off, const int* __restrict__ cnt,
                  const int* __restrict__ es,
                  const float* __restrict__ Win, const float* __restrict__ bin,
                  unsigned short* __restrict__ agg) {
  constexpr int C = 2048;
  constexpr int V = 8;
  int i = blockIdx.x;
  int c = threadIdx.x * V;
  float w0[V], w1[V], bb[V], acc[V];
#pragma unroll
  for (int j = 0; j < V; ++j) {
    w0[j] = Win[c + j]; w1[j] = Win[C + c + j]; bb[j] = bin[c + j]; acc[j] = 0.f;
  }
  float2 pd = *reinterpret_cast<const float2*>(pos + 2 * i);
  int s0 = off[i], n = cnt[i];   // n is block-uniform

  float2 r0, r1, r2, r3;
  int4 q0, q1, q2, q3;
  auto ld = [&](int k, float2& r, int4& q) {
    if (k < n) {
      int s = es[s0 + k];
      float2 ps = *reinterpret_cast<const float2*>(pos + 2 * s);
      r = make_float2(ps.x - pd.x, ps.y - pd.y);
      q = *reinterpret_cast<const int4*>(x + (size_t)s * C + c);
    }
  };
  auto fma8 = [&](const float2& r, const int4& q) {
    float xv[V] = { blo(q.x), bhi(q.x), blo(q.y), bhi(q.y),
                    blo(q.z), bhi(q.z), blo(q.w), bhi(q.w) };
#pragma unroll
    for (int j = 0; j < V; ++j) {
      float sc = fmaxf(fmaf(r.x, w0[j], fmaf(r.y, w1[j], bb[j])), 0.f);
      acc[j] = fmaf(sc, xv[j], acc[j]);
    }
  };
  ld(0, r0, q0); ld(1, r1, q1); ld(2, r2, q2); ld(3, r3, q3);
  for (int k = 0; k < n; k += 4) {
    fma8(r0, q0); ld(k + 4, r0, q0);
    if (k + 1 < n) { fma8(r1, q1); } ld(k + 5, r1, q1);
    if (k + 2 < n) { fma8(r2, q2); } ld(k + 6, r2, q2);
    if (k + 3 < n) { fma8(r3, q3); } ld(k + 7, r3, q3);
  }
  store8b(agg + (size_t)i * C + c, acc);
}

// ============ 128x128 4-wave MFMA GEMM, double-buffered, 5 blocks/CU ============
// out = relu(A[M,K] @ BT[N,K]^T + bias). A, BT bf16 (ushort).
// BK=32, 32 KiB static LDS (2 bufs x (A 8KB + B 8KB)), stage 1 K-tile ahead,
// counted vmcnt(4) (drains to 0 only on last iter), raw s_barrier, setprio.
// LDS chunk swizzle: logical k-chunk g of row r at slot g ^ ((r>>1)&3)
// (pre-swizzled global source + swizzled fragment-read address; involution).
// XCD-chunked bijective block swizzle (grids are multiples of 8).
// 5 blocks/CU: LDS 5*32KB = 160KB exactly; regs ~100 VGPR + 64 AGPR << cap.
template <typename OT>
__global__ __launch_bounds__(256, 5)
void gemm128(const unsigned short* __restrict__ A,
             const unsigned short* __restrict__ BT,
             const float* __restrict__ bias, OT* __restrict__ out,
             int M, int N, int K) {
  __shared__ unsigned short lds[16384];  // shorts: A bufs @0,4096; B bufs @8192,12288
  const int t = threadIdx.x;
  const int lane = t & 63, wid = t >> 6;
  const int wr = wid >> 1, wc = wid & 1;          // 2 x 2 wave grid, 64x64 each

  // XCD-chunked bijective swizzle (nwg % 8 == 0 for all our grids)
  const int nwg = gridDim.x * gridDim.y;
  const int orig = blockIdx.y * gridDim.x + blockIdx.x;
  const int swz = (orig & 7) * (nwg >> 3) + (orig >> 3);
  const int bx = swz % gridDim.x, by = swz / gridDim.x;
  const int m0 = by * 128, n0 = bx * 128;
  const int nk = K >> 5;

  // staging: 512 chunks of 16B per 128x32 tile; thread t does chunks t, t+256
  // chunk c: row = c>>2, stored slot g = c&3, source k-chunk = g ^ ((row>>1)&3)
  const int srow = t >> 2;                        // 0..63 (and +64)
  const int scg = (t & 3) ^ ((srow >> 1) & 3);
  const unsigned short* gA = A + (size_t)(m0 + srow) * K + scg * 8;
  const unsigned short* gB = BT + (size_t)(n0 + srow) * K + scg * 8;
  const size_t gH = (size_t)K << 6;               // 64 rows * K elements

#define STAGE(buf, kt) { \
    const unsigned short* gA_ = gA + ((size_t)(kt) << 5); \
    const unsigned short* gB_ = gB + ((size_t)(kt) << 5); \
    unsigned short* lA_ = lds + (buf) * 4096 + t * 8; \
    unsigned short* lB_ = lds + 8192 + (buf) * 4096 + t * 8; \
    gload16(gA_, lA_); gload16(gA_ + gH, lA_ + 2048); \
    gload16(gB_, lB_); gload16(gB_ + gH, lB_ + 2048); }

  // fragment reads: row = wbase + (lane&15), logical k-chunk = lane>>4,
  // slot = (lane>>4) ^ ((row>>1)&3); wbase multiples of 64 don't affect swizzle.
  const int frow = lane & 15;
  const int fswz = ((lane >> 4) ^ ((frow >> 1) & 3)) * 8;
  const int paOff = (wr * 64 + frow) * 32 + fswz;
  const int pbOff = 8192 + (wc * 64 + frow) * 32 + fswz;

  f32x4 acc[4][4];
#pragma unroll
  for (int m = 0; m < 4; ++m)
#pragma unroll
    for (int n = 0; n < 4; ++n) acc[m][n] = 0.f;

  STAGE(0, 0);  // prologue: 4 loads outstanding

  int cur = 0;
  for (int kt = 0; kt < nk; ++kt) {
    if (kt + 1 < nk) {
      STAGE(cur ^ 1, kt + 1);
      asm volatile("s_waitcnt vmcnt(4)" ::: "memory");  // kt's 4 loads landed
    } else {
      asm volatile("s_waitcnt vmcnt(0)" ::: "memory");
    }
    asm volatile("s_barrier" ::: "memory");  // all waves: tile kt staged
    const unsigned short* pa = lds + cur * 4096 + paOff;
    const unsigned short* pb = lds + cur * 4096 + pbOff;
    bf16x8 af[4], bf[4];
#pragma unroll
    for (int f = 0; f < 4; ++f) {
      af[f] = *reinterpret_cast<const bf16x8*>(pa + f * 512);   // +16 rows
      bf[f] = *reinterpret_cast<const bf16x8*>(pb + f * 512);
    }
    __builtin_amdgcn_s_setprio(1);
#pragma unroll
    for (int m = 0; m < 4; ++m)
#pragma unroll
      for (int n = 0; n < 4; ++n)
        acc[m][n] = __builtin_amdgcn_mfma_f32_16x16x32_bf16(
            af[m], bf[n], acc[m][n], 0, 0, 0);
    __builtin_amdgcn_s_setprio(0);
    asm volatile("s_barrier" ::: "memory");  // reads of cur done before overwrite
    cur ^= 1;
  }
#undef STAGE

  // epilogue: C/D layout col=lane&15, row=(lane>>4)*4+reg
  const int ccol = lane & 15;
  const int crow = (lane >> 4) * 4;
  float bv[4];
#pragma unroll
  for (int n = 0; n < 4; ++n)
    bv[n] = bias[n0 + wc * 64 + n * 16 + ccol];
#pragma unroll
  for (int m = 0; m < 4; ++m) {
    int gm0 = m0 + wr * 64 + m * 16 + crow;
#pragma unroll
    for (int r = 0; r < 4; ++r) {
      int gm = gm0 + r;
      if (gm < M) {
        size_t base = (size_t)gm * N + n0 + wc * 64 + ccol;
#pragma unroll
        for (int n = 0; n < 4; ++n)
          st1(out + base + n * 16, fmaxf(acc[m][n][r] + bv[n], 0.f));
      }
    }
  }
}

// ---------- row-wise L2 normalize, C=1024 ----------
__global__ __launch_bounds__(256)
void l2norm_kernel(float* __restrict__ out) {
  constexpr int C = 1024;
  float* p = out + (size_t)blockIdx.x * C;
  float4 v = *reinterpret_cast<const float4*>(p + threadIdx.x * 4);
  float s = v.x * v.x + v.y * v.y + v.z * v.z + v.w * v.w;
#pragma unroll
  for (int o = 32; o > 0; o >>= 1) s += __shfl_down(s, o);
  __shared__ float wsum[4];
  if ((threadIdx.x & 63) == 0) wsum[threadIdx.x >> 6] = s;
  __syncthreads();
  float tot = wsum[0] + wsum[1] + wsum[2] + wsum[3];
  float inv = 1.0f / fmaxf(sqrtf(tot), 1e-12f);
  float4 r = make_float4(v.x * inv, v.y * inv, v.z * inv, v.w * inv);
  *reinterpret_cast<float4*>(p + threadIdx.x * 4) = r;
}

extern "C" void kernel_launch(void* const* d_in, const int* in_sizes, int n_in,
                              void* d_out, int out_size, void* d_ws, size_t ws_size,
                              hipStream_t stream) {
  (void)in_sizes; (void)n_in; (void)out_size; (void)ws_size;
  const float* x     = (const float*)d_in[0];
  const float* pos   = (const float*)d_in[1];
  const int*   ei    = (const int*)d_in[2];
  const int*   srcv  = ei;            // edge_index[0] (j)
  const int*   dstv  = ei + NE;       // edge_index[1] (i)
  const float* Win1  = (const float*)d_in[3];
  const float* bin1  = (const float*)d_in[4];
  const float* Wout1 = (const float*)d_in[5];
  const float* bout1 = (const float*)d_in[6];
  const float* Win2  = (const float*)d_in[7];
  const float* bin2  = (const float*)d_in[8];
  const float* Wout2 = (const float*)d_in[9];
  const float* bout2 = (const float*)d_in[10];
  const float* Win3  = (const float*)d_in[11];
  const float* bin3  = (const float*)d_in[12];
  const float* Wout3 = (const float*)d_in[13];
  const float* bout3 = (const float*)d_in[14];
  float* outp = (float*)d_out;

  // workspace layout (~96.4 MB; 123 MB proven safe in round 1)
  char* ws = (char*)d_ws;
  unsigned short* aggb = (unsigned short*)ws;                    // 10240*2048*2 = 41,943,040
  unsigned short* h1   = (unsigned short*)(ws + 41943040);       // 10000*2048*2 = 40,960,000
  unsigned short* W2T  = (unsigned short*)(ws + 82903040);       // 2048*2048*2  =  8,388,608
  unsigned short* W3T  = (unsigned short*)(ws + 91291648);       // 1024*2048*2  =  4,194,304
  unsigned short* W1T  = (unsigned short*)(ws + 95485952);       // 2048*128*2   =    524,288
  int* cnt    = (int*)(ws + 96010240);
  int* off    = (int*)(ws + 96050240);
  int* cursor = (int*)(ws + 96090240);
  int* es     = (int*)(ws + 96130240);                           // 320,000
  // h2 bf16 [NN,2048] = 40,960,000 B lives in d_out; dead before GEMM3 overwrites it
  unsigned short* h2 = (unsigned short*)d_out;

  const dim3 blk(256);
  const int eb = (NE + 255) / 256;

  // ---- CSR build ----
  hipMemsetAsync(cnt, 0, NN * sizeof(int), stream);
  hist_kernel<<<eb, blk, 0, stream>>>(dstv, cnt);
  scan_kernel<<<1, blk, 0, stream>>>(cnt, off, cursor);
  bucket_kernel<<<eb, blk, 0, stream>>>(srcv, dstv, cursor, es);

  // ---- weight transposes (f32 -> bf16, [K][N] -> [N][K]) ----
  transpose_w<<<dim3(2048 / 32, 128 / 32),  blk, 0, stream>>>(Wout1, W1T, 128, 2048);
  transpose_w<<<dim3(2048 / 32, 2048 / 32), blk, 0, stream>>>(Wout2, W2T, 2048, 2048);
  transpose_w<<<dim3(1024 / 32, 2048 / 32), blk, 0, stream>>>(Wout3, W3T, 2048, 1024);

  // zero the 240 pad rows of aggb once per call (gathers never touch them)
  hipMemsetAsync(aggb + (size_t)NN * 2048, 0, (size_t)(AGG_ROWS - NN) * 2048 * 2, stream);

  // ---- layer 1: 128 -> 2048 ----
  gather_l1<<<(NN + 3) / 4, blk, 0, stream>>>(x, pos, off, cnt, es, Win1, bin1, aggb);
  gemm128<unsigned short><<<dim3(2048 / 128, AGG_ROWS / 128), blk, 0, stream>>>(
      aggb, W1T, bout1, h1, NN, 2048, 128);

  // ---- layer 2: 2048 -> 2048 ----
  gather_c2048<<<NN, blk, 0, stream>>>(h1, pos, off, cnt, es, Win2, bin2, aggb);
  gemm128<unsigned short><<<dim3(2048 / 128, AGG_ROWS / 128), blk, 0, stream>>>(
      aggb, W2T, bout2, h2, NN, 2048, 2048);

  // ---- layer 3: 2048 -> 1024 ----
  gather_c2048<<<NN, blk, 0, stream>>>(h2, pos, off, cnt, es, Win3, bin3, aggb);
  gemm128<float><<<dim3(1024 / 128, AGG_ROWS / 128), blk, 0, stream>>>(
      aggb, W3T, bout3, outp, NN, 1024, 2048);

  // ---- final L2 normalize ----
  l2norm_kernel<<<NN, blk, 0, stream>>>(outp);
}

// Round 7
// 347.294 us; speedup vs baseline: 3.0248x; 3.0248x over previous
//
#include <hip/hip_runtime.h>
#include <hip/hip_bf16.h>

#define DEVI __device__ __forceinline__

constexpr int NN = 10000;       // nodes
constexpr int NE = 80000;       // edges
constexpr int AGG_ROWS = 10240; // 64 * 160 — pad so 160-row M-tiles stay in-bounds

typedef __attribute__((ext_vector_type(8))) short bf16x8;  // 8 bf16 (4 VGPRs)
typedef __attribute__((ext_vector_type(4))) float f32x4;   // MFMA acc

// ---------- bf16 helpers (bit-level, RNE) ----------
DEVI float blo(unsigned int u) {
  union { unsigned int i; float f; } c; c.i = u << 16; return c.f;
}
DEVI float bhi(unsigned int u) {
  union { unsigned int i; float f; } c; c.i = u & 0xffff0000u; return c.f;
}
DEVI unsigned short f2b(float f) {
  union { float f; unsigned int i; } c; c.f = f;
  unsigned int i = c.i;
  return (unsigned short)((i + 0x7fffu + ((i >> 16) & 1u)) >> 16);
}
DEVI void st1(float* p, float v) { *p = v; }
DEVI void st1(unsigned short* p, float v) { *p = f2b(v); }
DEVI void store8b(unsigned short* p, const float v[8]) {
  int4 pk;
  pk.x = (int)((unsigned)f2b(v[0]) | ((unsigned)f2b(v[1]) << 16));
  pk.y = (int)((unsigned)f2b(v[2]) | ((unsigned)f2b(v[3]) << 16));
  pk.z = (int)((unsigned)f2b(v[4]) | ((unsigned)f2b(v[5]) << 16));
  pk.w = (int)((unsigned)f2b(v[6]) | ((unsigned)f2b(v[7]) << 16));
  *reinterpret_cast<int4*>(p) = pk;
}

// async global->LDS, 16B per lane (wave-uniform LDS base + lane*16 pattern)
DEVI void gload16(const void* g, void* l) {
  __builtin_amdgcn_global_load_lds(
      (const __attribute__((address_space(1))) void*)g,
      (__attribute__((address_space(3))) void*)l, 16, 0, 0);
}

// ================= CSR build =================
__global__ __launch_bounds__(256)
void hist_kernel(const int* __restrict__ dst, int* __restrict__ cnt) {
  int e = blockIdx.x * 256 + threadIdx.x;
  if (e < NE) atomicAdd(&cnt[dst[e]], 1);
}

__global__ __launch_bounds__(256)
void scan_kernel(const int* __restrict__ cnt, int* __restrict__ off,
                 int* __restrict__ cursor) {
  __shared__ int buf[256];
  __shared__ int carry;
  if (threadIdx.x == 0) carry = 0;
  __syncthreads();
  for (int base = 0; base < NN; base += 256) {
    int i = base + threadIdx.x;
    int v = (i < NN) ? cnt[i] : 0;
    buf[threadIdx.x] = v;
    __syncthreads();
#pragma unroll
    for (int o = 1; o < 256; o <<= 1) {
      int t = (threadIdx.x >= o) ? buf[threadIdx.x - o] : 0;
      __syncthreads();
      buf[threadIdx.x] += t;
      __syncthreads();
    }
    int incl = buf[threadIdx.x];
    int c0 = carry;
    if (i < NN) { int ex = c0 + incl - v; off[i] = ex; cursor[i] = ex; }
    __syncthreads();
    if (threadIdx.x == 255) carry = c0 + incl;
    __syncthreads();
  }
}

__global__ __launch_bounds__(256)
void bucket_kernel(const int* __restrict__ src, const int* __restrict__ dst,
                   int* __restrict__ cursor, int* __restrict__ es) {
  int e = blockIdx.x * 256 + threadIdx.x;
  if (e < NE) {
    int p = atomicAdd(&cursor[dst[e]], 1);
    es[p] = src[e];
  }
}

// ============ weight convert+transpose: W[K][N] f32 -> WT[N][K] bf16 ============
__global__ __launch_bounds__(256)
void transpose_w(const float* __restrict__ W, unsigned short* __restrict__ WT,
                 int K, int N) {
  __shared__ float tile[32][33];
  int tx = threadIdx.x & 31, ty = threadIdx.x >> 5;  // ty 0..7
  int n0 = blockIdx.x * 32, k0 = blockIdx.y * 32;
#pragma unroll
  for (int j = 0; j < 32; j += 8)
    tile[ty + j][tx] = W[(size_t)(k0 + ty + j) * N + n0 + tx];
  __syncthreads();
#pragma unroll
  for (int j = 0; j < 32; j += 8)
    WT[(size_t)(n0 + ty + j) * K + k0 + tx] = f2b(tile[tx][ty + j]);
}

// ================= gather-aggregate (CSR, no atomics, depth-4 edge pipeline) =================
// layer 1: C=128, x f32. One 64-lane wave per node, 2 ch/lane. bf16 out.
__global__ __launch_bounds__(256)
void gather_l1(const float* __restrict__ x, const float* __restrict__ pos,
               const int* __restrict__ off, const int* __restrict__ cnt,
               const int* __restrict__ es,
               const float* __restrict__ Win, const float* __restrict__ bin,
               unsigned short* __restrict__ agg) {
  constexpr int C = 128;
  int lane = threadIdx.x & 63;
  int i = blockIdx.x * 4 + (threadIdx.x >> 6);
  if (i >= NN) return;
  int c = lane * 2;
  float w00 = Win[c], w01 = Win[c + 1];
  float w10 = Win[C + c], w11 = Win[C + c + 1];
  float b0 = bin[c], b1 = bin[c + 1];
  float a0 = 0.f, a1 = 0.f;
  float2 pd = *reinterpret_cast<const float2*>(pos + 2 * i);
  int s0 = off[i], n = cnt[i];   // n is wave-uniform (one node per wave)

  float2 r0, r1, r2, r3, q0, q1, q2, q3;
  auto ld = [&](int k, float2& r, float2& q) {
    if (k < n) {
      int s = es[s0 + k];
      float2 ps = *reinterpret_cast<const float2*>(pos + 2 * s);
      r = make_float2(ps.x - pd.x, ps.y - pd.y);
      q = *reinterpret_cast<const float2*>(x + (size_t)s * C + c);
    }
  };
  auto fma1 = [&](const float2& r, const float2& q) {
    float sc0 = fmaxf(fmaf(r.x, w00, fmaf(r.y, w10, b0)), 0.f);
    float sc1 = fmaxf(fmaf(r.x, w01, fmaf(r.y, w11, b1)), 0.f);
    a0 = fmaf(sc0, q.x, a0);
    a1 = fmaf(sc1, q.y, a1);
  };
  ld(0, r0, q0); ld(1, r1, q1); ld(2, r2, q2); ld(3, r3, q3);
  for (int k = 0; k < n; k += 4) {
    fma1(r0, q0); ld(k + 4, r0, q0);
    if (k + 1 < n) { fma1(r1, q1); } ld(k + 5, r1, q1);
    if (k + 2 < n) { fma1(r2, q2); } ld(k + 6, r2, q2);
    if (k + 3 < n) { fma1(r3, q3); } ld(k + 7, r3, q3);
  }
  unsigned int pk = (unsigned)f2b(a0) | ((unsigned)f2b(a1) << 16);
  *reinterpret_cast<unsigned int*>(agg + (size_t)i * C + c) = pk;
}

// layers 2/3: C=2048, x bf16. One 256-thread block per node, 8 ch/thread. bf16 out.
__global__ __launch_bounds__(256)
void gather_c2048(const unsigned short* __restrict__ x, const float* __restrict__ pos,
                  const int* __restrict__ off, const int* __restrict__ cnt,
                  const int* __restrict__ es,
                  const float* __restrict__ Win, const float* __restrict__ bin,
                  unsigned short* __restrict__ agg) {
  constexpr int C = 2048;
  constexpr int V = 8;
  int i = blockIdx.x;
  int c = threadIdx.x * V;
  float w0[V], w1[V], bb[V], acc[V];
#pragma unroll
  for (int j = 0; j < V; ++j) {
    w0[j] = Win[c + j]; w1[j] = Win[C + c + j]; bb[j] = bin[c + j]; acc[j] = 0.f;
  }
  float2 pd = *reinterpret_cast<const float2*>(pos + 2 * i);
  int s0 = off[i], n = cnt[i];   // n is block-uniform

  float2 r0, r1, r2, r3;
  int4 q0, q1, q2, q3;
  auto ld = [&](int k, float2& r, int4& q) {
    if (k < n) {
      int s = es[s0 + k];
      float2 ps = *reinterpret_cast<const float2*>(pos + 2 * s);
      r = make_float2(ps.x - pd.x, ps.y - pd.y);
      q = *reinterpret_cast<const int4*>(x + (size_t)s * C + c);
    }
  };
  auto fma8 = [&](const float2& r, const int4& q) {
    float xv[V] = { blo(q.x), bhi(q.x), blo(q.y), bhi(q.y),
                    blo(q.z), bhi(q.z), blo(q.w), bhi(q.w) };
#pragma unroll
    for (int j = 0; j < V; ++j) {
      float sc = fmaxf(fmaf(r.x, w0[j], fmaf(r.y, w1[j], bb[j])), 0.f);
      acc[j] = fmaf(sc, xv[j], acc[j]);
    }
  };
  ld(0, r0, q0); ld(1, r1, q1); ld(2, r2, q2); ld(3, r3, q3);
  for (int k = 0; k < n; k += 4) {
    fma8(r0, q0); ld(k + 4, r0, q0);
    if (k + 1 < n) { fma8(r1, q1); } ld(k + 5, r1, q1);
    if (k + 2 < n) { fma8(r2, q2); } ld(k + 6, r2, q2);
    if (k + 3 < n) { fma8(r3, q3); } ld(k + 7, r3, q3);
  }
  store8b(agg + (size_t)i * C + c, acc);
}

// ============ 160x128 4-wave MFMA GEMM, BK=64, zero-tail grids ============
// out = relu(A[M,K] @ BT[N,K]^T + bias). A, BT bf16 (ushort).
// 4 waves (2x2), per-wave 80x64 output (5x4 frags, 80 acc regs).
// LDS 72 KiB dynamic (dbuf x (A 20KB + B 16KB)); 2 blocks/CU (144<=160KB,
// ~160 unified regs <= 256-reg cap at 2 waves/SIMD -> launch_bounds(256,2)).
// Grids: L2/L1 16x64=1024 = 2 exact rounds of 512; L3 8x64=512 = 1 round.
// Staging: 9 wave-gloads per wave per K-tile (A 20KB=20, B 16KB=16, /4 waves),
// counted vmcnt(9), drains to 0 only on last iter. Raw s_barrier, setprio.
// LDS swizzle: 8 slots/row (16B each); slot s of row r holds k-chunk s^(r&7);
// applied on pre-swizzled global source AND fragment-read address (involution).
template <typename OT>
__global__ __launch_bounds__(256, 2)
void gemm160(const unsigned short* __restrict__ A,
             const unsigned short* __restrict__ BT,
             const float* __restrict__ bias, OT* __restrict__ out,
             int M, int N, int K) {
  extern __shared__ unsigned short lds[];  // A: [2][10240] @0; B: [2][8192] @20480
  const int t = threadIdx.x;
  const int lane = t & 63, wid = t >> 6;
  const int wr = wid >> 1, wc = wid & 1;          // 2x2 wave grid, 80x64 each

  // XCD-chunked bijective swizzle (nwg % 8 == 0 for all our grids)
  const int nwg = gridDim.x * gridDim.y;
  const int orig = blockIdx.y * gridDim.x + blockIdx.x;
  const int swz = (orig & 7) * (nwg >> 3) + (orig >> 3);
  const int bx = swz % gridDim.x, by = swz / gridDim.x;
  const int m0 = by * 160, n0 = bx * 128;
  const int nk = K >> 6;

  // staging: wave w covers A gloads w*5..w*5+4 (8 rows each), B gloads w*4..w*4+3.
  // lane covers row (gload_row_base + lane>>3), written slot lane&7;
  // source k-chunk = (lane&7) ^ ((lane>>3)&7)  (row&7 == lane>>3 for all gloads).
  const int lrow = lane >> 3;              // 0..7
  const int schunk = (lane & 7) ^ lrow;    // pre-swizzled source k-chunk
  const unsigned short* gA = A + (size_t)(m0 + wid * 40 + lrow) * K + schunk * 8;
  const unsigned short* gB = BT + (size_t)(n0 + wid * 32 + lrow) * K + schunk * 8;
  unsigned short* lA = lds + (wid * 5) * 512 + lane * 8;          // +jj*512
  unsigned short* lB = lds + 20480 + (wid * 4) * 512 + lane * 8;  // +jj*512

  auto STAGE = [&](int buf, int kt) {
    const size_t ko = (size_t)kt << 6;
#pragma unroll
    for (int jj = 0; jj < 5; ++jj)
      gload16(gA + (size_t)(jj * 8) * K + ko, lA + buf * 10240 + jj * 512);
#pragma unroll
    for (int jj = 0; jj < 4; ++jj)
      gload16(gB + (size_t)(jj * 8) * K + ko, lB + buf * 8192 + jj * 512);
  };

  // fragment reads: row = wbase + fm*16 + frow (wbase,fm*16 ≡ 0 mod 8);
  // k-chunk c = ks*4 + (lane>>4); slot = c ^ (frow&7).
  const int frow = lane & 15;
  const int fr7 = frow & 7;
  const int slot0 = ((lane >> 4) ^ fr7) * 8;        // ks=0, elems
  const int slot1 = ((4 + (lane >> 4)) ^ fr7) * 8;  // ks=1
  const int paRow = (wr * 80 + frow) * 64;
  const int pbRow = (wc * 64 + frow) * 64;

  f32x4 acc[5][4];
#pragma unroll
  for (int m = 0; m < 5; ++m)
#pragma unroll
    for (int n = 0; n < 4; ++n) acc[m][n] = 0.f;

  STAGE(0, 0);  // prologue: 9 loads outstanding

  int cur = 0;
  for (int kt = 0; kt < nk; ++kt) {
    if (kt + 1 < nk) {
      STAGE(cur ^ 1, kt + 1);
      asm volatile("s_waitcnt vmcnt(9)" ::: "memory");  // kt's 9 loads landed
    } else {
      asm volatile("s_waitcnt vmcnt(0)" ::: "memory");
    }
    asm volatile("s_barrier" ::: "memory");  // all waves: tile kt staged
    const unsigned short* pa = lds + cur * 10240 + paRow;
    const unsigned short* pb = lds + 20480 + cur * 8192 + pbRow;
#pragma unroll
    for (int ks = 0; ks < 2; ++ks) {
      const int sl = ks ? slot1 : slot0;
      bf16x8 af[5], bf[4];
#pragma unroll
      for (int m = 0; m < 5; ++m)
        af[m] = *reinterpret_cast<const bf16x8*>(pa + m * 1024 + sl);
#pragma unroll
      for (int n = 0; n < 4; ++n)
        bf[n] = *reinterpret_cast<const bf16x8*>(pb + n * 1024 + sl);
      __builtin_amdgcn_s_setprio(1);
#pragma unroll
      for (int m = 0; m < 5; ++m)
#pragma unroll
        for (int n = 0; n < 4; ++n)
          acc[m][n] = __builtin_amdgcn_mfma_f32_16x16x32_bf16(
              af[m], bf[n], acc[m][n], 0, 0, 0);
      __builtin_amdgcn_s_setprio(0);
    }
    asm volatile("s_barrier" ::: "memory");  // reads of cur done before overwrite
    cur ^= 1;
  }

  // epilogue: C/D layout col=lane&15, row=(lane>>4)*4+reg
  const int ccol = lane & 15;
  const int crow = (lane >> 4) * 4;
  float bv[4];
#pragma unroll
  for (int n = 0; n < 4; ++n)
    bv[n] = bias[n0 + wc * 64 + n * 16 + ccol];
#pragma unroll
  for (int m = 0; m < 5; ++m) {
    int gm0 = m0 + wr * 80 + m * 16 + crow;
#pragma unroll
    for (int r = 0; r < 4; ++r) {
      int gm = gm0 + r;
      if (gm < M) {
        size_t base = (size_t)gm * N + n0 + wc * 64 + ccol;
#pragma unroll
        for (int n = 0; n < 4; ++n)
          st1(out + base + n * 16, fmaxf(acc[m][n][r] + bv[n], 0.f));
      }
    }
  }
}

// ---------- row-wise L2 normalize, C=1024 ----------
__global__ __launch_bounds__(256)
void l2norm_kernel(float* __restrict__ out) {
  constexpr int C = 1024;
  float* p = out + (size_t)blockIdx.x * C;
  float4 v = *reinterpret_cast<const float4*>(p + threadIdx.x * 4);
  float s = v.x * v.x + v.y * v.y + v.z * v.z + v.w * v.w;
#pragma unroll
  for (int o = 32; o > 0; o >>= 1) s += __shfl_down(s, o);
  __shared__ float wsum[4];
  if ((threadIdx.x & 63) == 0) wsum[threadIdx.x >> 6] = s;
  __syncthreads();
  float tot = wsum[0] + wsum[1] + wsum[2] + wsum[3];
  float inv = 1.0f / fmaxf(sqrtf(tot), 1e-12f);
  float4 r = make_float4(v.x * inv, v.y * inv, v.z * inv, v.w * inv);
  *reinterpret_cast<float4*>(p + threadIdx.x * 4) = r;
}

extern "C" void kernel_launch(void* const* d_in, const int* in_sizes, int n_in,
                              void* d_out, int out_size, void* d_ws, size_t ws_size,
                              hipStream_t stream) {
  (void)in_sizes; (void)n_in; (void)out_size; (void)ws_size;
  const float* x     = (const float*)d_in[0];
  const float* pos   = (const float*)d_in[1];
  const int*   ei    = (const int*)d_in[2];
  const int*   srcv  = ei;            // edge_index[0] (j)
  const int*   dstv  = ei + NE;       // edge_index[1] (i)
  const float* Win1  = (const float*)d_in[3];
  const float* bin1  = (const float*)d_in[4];
  const float* Wout1 = (const float*)d_in[5];
  const float* bout1 = (const float*)d_in[6];
  const float* Win2  = (const float*)d_in[7];
  const float* bin2  = (const float*)d_in[8];
  const float* Wout2 = (const float*)d_in[9];
  const float* bout2 = (const float*)d_in[10];
  const float* Win3  = (const float*)d_in[11];
  const float* bin3  = (const float*)d_in[12];
  const float* Wout3 = (const float*)d_in[13];
  const float* bout3 = (const float*)d_in[14];
  float* outp = (float*)d_out;

  // workspace layout (~96.4 MB; 123 MB proven safe in round 1)
  char* ws = (char*)d_ws;
  unsigned short* aggb = (unsigned short*)ws;                    // 10240*2048*2 = 41,943,040
  unsigned short* h1   = (unsigned short*)(ws + 41943040);       // 10000*2048*2 = 40,960,000
  unsigned short* W2T  = (unsigned short*)(ws + 82903040);       // 2048*2048*2  =  8,388,608
  unsigned short* W3T  = (unsigned short*)(ws + 91291648);       // 1024*2048*2  =  4,194,304
  unsigned short* W1T  = (unsigned short*)(ws + 95485952);       // 2048*128*2   =    524,288
  int* cnt    = (int*)(ws + 96010240);
  int* off    = (int*)(ws + 96050240);
  int* cursor = (int*)(ws + 96090240);
  int* es     = (int*)(ws + 96130240);                           // 320,000
  // h2 bf16 [NN,2048] = 40,960,000 B lives in d_out; dead before GEMM3 overwrites it
  unsigned short* h2 = (unsigned short*)d_out;

  // 72 KiB dynamic LDS for the GEMM (host-side attribute; graph-capture safe,
  // proven in round 3)
  hipFuncSetAttribute((const void*)gemm160<unsigned short>,
                      hipFuncAttributeMaxDynamicSharedMemorySize, 73728);
  hipFuncSetAttribute((const void*)gemm160<float>,
                      hipFuncAttributeMaxDynamicSharedMemorySize, 73728);

  const dim3 blk(256);
  const int eb = (NE + 255) / 256;

  // ---- CSR build ----
  hipMemsetAsync(cnt, 0, NN * sizeof(int), stream);
  hist_kernel<<<eb, blk, 0, stream>>>(dstv, cnt);
  scan_kernel<<<1, blk, 0, stream>>>(cnt, off, cursor);
  bucket_kernel<<<eb, blk, 0, stream>>>(srcv, dstv, cursor, es);

  // ---- weight transposes (f32 -> bf16, [K][N] -> [N][K]) ----
  transpose_w<<<dim3(2048 / 32, 128 / 32),  blk, 0, stream>>>(Wout1, W1T, 128, 2048);
  transpose_w<<<dim3(2048 / 32, 2048 / 32), blk, 0, stream>>>(Wout2, W2T, 2048, 2048);
  transpose_w<<<dim3(1024 / 32, 2048 / 32), blk, 0, stream>>>(Wout3, W3T, 2048, 1024);

  // zero the 240 pad rows of aggb once per call (gathers never touch them)
  hipMemsetAsync(aggb + (size_t)NN * 2048, 0, (size_t)(AGG_ROWS - NN) * 2048 * 2, stream);

  // ---- layer 1: 128 -> 2048 ----
  gather_l1<<<(NN + 3) / 4, blk, 0, stream>>>(x, pos, off, cnt, es, Win1, bin1, aggb);
  gemm160<unsigned short><<<dim3(2048 / 128, AGG_ROWS / 160), blk, 73728, stream>>>(
      aggb, W1T, bout1, h1, NN, 2048, 128);

  // ---- layer 2: 2048 -> 2048 ----
  gather_c2048<<<NN, blk, 0, stream>>>(h1, pos, off, cnt, es, Win2, bin2, aggb);
  gemm160<unsigned short><<<dim3(2048 / 128, AGG_ROWS / 160), blk, 73728, stream>>>(
      aggb, W2T, bout2, h2, NN, 2048, 2048);

  // ---- layer 3: 2048 -> 1024 ----
  gather_c2048<<<NN, blk, 0, stream>>>(h2, pos, off, cnt, es, Win3, bin3, aggb);
  gemm160<float><<<dim3(1024 / 128, AGG_ROWS / 160), blk, 73728, stream>>>(
      aggb, W3T, bout3, outp, NN, 1024, 2048);

  // ---- final L2 normalize ----
  l2norm_kernel<<<NN, blk, 0, stream>>>(outp);
}